// Round 1
// baseline (806.909 us; speedup 1.0000x reference)
//
#include <hip/hip_runtime.h>

#define B_ 4
#define S_ 2048
#define D_ 1024
#define H_ 16
#define KD_ 64
#define P_ 1024
#define M_ (B_*S_)

typedef unsigned short u16;
typedef unsigned int u32;
typedef __attribute__((ext_vector_type(4))) float f32x4;
typedef __attribute__((ext_vector_type(8))) __bf16 bf16x8;

__device__ __forceinline__ u16 f2bf(float f) {
  u32 x = __float_as_uint(f);
  return (u16)((x + 0x7fffu + ((x >> 16) & 1u)) >> 16);
}

__device__ __forceinline__ void gl_lds16(const u16* g, u16* l) {
  __builtin_amdgcn_global_load_lds((__attribute__((address_space(1))) void*)g,
                                   (__attribute__((address_space(3))) void*)l, 16, 0, 0);
}

// ---------------- fp32 -> bf16 convert (vectorized) ----------------
__global__ void cvt_bf16_kernel(const float* __restrict__ in, u16* __restrict__ out, int n4) {
  int i = blockIdx.x * 256 + threadIdx.x;
  if (i >= n4) return;
  float4 v = ((const float4*)in)[i];
  u32 w0 = (u32)f2bf(v.x) | ((u32)f2bf(v.y) << 16);
  u32 w1 = (u32)f2bf(v.z) | ((u32)f2bf(v.w) << 16);
  ((u32*)out)[i*2+0] = w0;
  ((u32*)out)[i*2+1] = w1;
}

// ---------------- transpose 1024x1024 fp32 -> bf16 [C][R] ----------------
__global__ void transpose_cvt(const float* __restrict__ in, u16* __restrict__ out) {
  __shared__ float tile[32][33];
  int bx = blockIdx.x * 32, by = blockIdx.y * 32;
  int tx = threadIdx.x, ty = threadIdx.y; // block (32,8)
  #pragma unroll
  for (int kk = 0; kk < 4; ++kk)
    tile[ty + kk*8][tx] = in[(by + ty + kk*8) * 1024 + bx + tx];
  __syncthreads();
  #pragma unroll
  for (int kk = 0; kk < 4; ++kk)
    out[(bx + ty + kk*8) * 1024 + by + tx] = f2bf(tile[tx][ty + kk*8]);
}

// ---------------- bf16 GEMM: C[M,N] = A[M,K] * Bt[N,K]^T + bias ----------------
// m97 pattern: 128x128 tile, BK=32, 4 waves each 64x64, global_load_lds width=16.
template<bool BF16_OUT>
__global__ __launch_bounds__(256) void gemm_bt(const u16* __restrict__ A,
                                               const u16* __restrict__ Bt,
                                               const float* __restrict__ bias,
                                               void* __restrict__ Cout)
{
  constexpr int K = 1024, N = 1024, BK = 32;
  __shared__ alignas(16) u16 As[128*BK];
  __shared__ alignas(16) u16 Bs[128*BK];
  const int tid = threadIdx.x;
  const int w = tid >> 6, l = tid & 63;
  const int quad = l >> 4, l16 = l & 15;
  const int wm = (w >> 1) * 64, wn = (w & 1) * 64;
  const long mBase = (long)blockIdx.x * 128;
  const int  nBase = blockIdx.y * 128;

  f32x4 acc[4][4] = {};
  const int off0 = w*1024 + l*16; // byte slot within staging pass

  for (int kb = 0; kb < K/BK; ++kb) {
    __syncthreads();               // prior iter done reading LDS
    #pragma unroll
    for (int p = 0; p < 2; ++p) {
      int off = p*4096 + off0;
      int row = off >> 6;          // 64 B per row of the 128x32 bf16 tile
      int cb  = off & 63;
      const u16* ga = A  + (mBase + row)*K + kb*BK + (cb >> 1);
      const u16* gb = Bt + ((long)(nBase + row))*K + kb*BK + (cb >> 1);
      gl_lds16(ga, (u16*)((char*)As + p*4096 + w*1024));
      gl_lds16(gb, (u16*)((char*)Bs + p*4096 + w*1024));
    }
    __syncthreads();               // staged data visible
    bf16x8 af[4], bf[4];
    #pragma unroll
    for (int i = 0; i < 4; ++i) af[i] = *(const bf16x8*)&As[(wm + i*16 + l16)*BK + quad*8];
    #pragma unroll
    for (int j = 0; j < 4; ++j) bf[j] = *(const bf16x8*)&Bs[(wn + j*16 + l16)*BK + quad*8];
    #pragma unroll
    for (int i = 0; i < 4; ++i)
      #pragma unroll
      for (int j = 0; j < 4; ++j)
        acc[i][j] = __builtin_amdgcn_mfma_f32_16x16x32_bf16(af[i], bf[j], acc[i][j], 0, 0, 0);
  }

  #pragma unroll
  for (int i = 0; i < 4; ++i)
    #pragma unroll
    for (int j = 0; j < 4; ++j)
      #pragma unroll
      for (int r = 0; r < 4; ++r) {
        long row = mBase + wm + i*16 + quad*4 + r;
        int  col = nBase + wn + j*16 + l16;
        float v = acc[i][j][r] + bias[col];
        if (BF16_OUT) ((u16*)Cout)[row*N + col] = f2bf(v);
        else          ((float*)Cout)[row*N + col] = v;
      }
}

// ---------------- flash attention with ALiBi + causal ----------------
// grid (qt=16, h=16, b=4), 256 threads (4 waves), wave w owns q-rows [w*32, w*32+32)
__global__ __launch_bounds__(256) void attn_kernel(const u16* __restrict__ Qb,
                                                   const u16* __restrict__ Kb,
                                                   const u16* __restrict__ Vb,
                                                   u16* __restrict__ Ob)
{
  const int qt = blockIdx.x, h = blockIdx.y, b = blockIdx.z;
  const int tid = threadIdx.x;
  const int w = tid >> 6, l = tid & 63;
  const int quad = l >> 4, l16 = l & 15;
  const float slope = exp2f(-0.5f * (float)(h + 1)); // H=16 -> slopes 2^{-(i+1)/2}

  __shared__ alignas(16) u16 Vs[64][128];     // [d][key] (transposed V tile)
  __shared__ alignas(16) u16 Ps[4][32][128];  // per-wave P tile (C/D -> A layout round-trip)

  const int qrow0 = qt*128 + w*32;

  // Q fragments held in registers for the whole kernel (A-operand layout)
  bf16x8 qf[2][2];
  #pragma unroll
  for (int i = 0; i < 2; ++i)
    #pragma unroll
    for (int kk = 0; kk < 2; ++kk)
      qf[i][kk] = *(const bf16x8*)&Qb[((long)(b*S_ + qrow0 + i*16 + l16))*P_ + h*KD_ + kk*32 + quad*8];

  f32x4 o[2][4] = {};
  float m_i[2][4], l_i[2][4];
  #pragma unroll
  for (int i = 0; i < 2; ++i)
    #pragma unroll
    for (int r = 0; r < 4; ++r) { m_i[i][r] = -1e30f; l_i[i][r] = 0.f; }

  for (int kt = 0; kt <= qt; ++kt) {   // causal: skip tiles fully above diagonal
    __syncthreads();                    // prior PV reads of Vs done
    // stage V tile transposed: Vs[d][key]
    #pragma unroll
    for (int it = 0; it < 4; ++it) {
      int c = it*256 + tid;            // 0..1023
      int kr = c >> 3, dc = c & 7;
      uint4 vv = *(const uint4*)&Vb[((long)(b*S_ + kt*128 + kr))*P_ + h*KD_ + dc*8];
      u32 u0 = vv.x, u1 = vv.y, u2 = vv.z, u3 = vv.w;
      Vs[dc*8+0][kr] = (u16)u0;  Vs[dc*8+1][kr] = (u16)(u0 >> 16);
      Vs[dc*8+2][kr] = (u16)u1;  Vs[dc*8+3][kr] = (u16)(u1 >> 16);
      Vs[dc*8+4][kr] = (u16)u2;  Vs[dc*8+5][kr] = (u16)(u2 >> 16);
      Vs[dc*8+6][kr] = (u16)u3;  Vs[dc*8+7][kr] = (u16)(u3 >> 16);
    }
    __syncthreads();

    // S = Q K^T  (K fragments direct from global; B-operand layout)
    f32x4 s[2][8];
    #pragma unroll
    for (int j = 0; j < 8; ++j) {
      const long krow = (long)(b*S_ + kt*128 + j*16 + l16);
      bf16x8 kf0 = *(const bf16x8*)&Kb[krow*P_ + h*KD_ + quad*8];
      bf16x8 kf1 = *(const bf16x8*)&Kb[krow*P_ + h*KD_ + 32 + quad*8];
      #pragma unroll
      for (int i = 0; i < 2; ++i) {
        f32x4 t = {};
        t = __builtin_amdgcn_mfma_f32_16x16x32_bf16(qf[i][0], kf0, t, 0, 0, 0);
        t = __builtin_amdgcn_mfma_f32_16x16x32_bf16(qf[i][1], kf1, t, 0, 0, 0);
        s[i][j] = t;
      }
    }

    const bool diag = (kt == qt);
    #pragma unroll
    for (int i = 0; i < 2; ++i) {
      // logits = s/8 + slope*(i-j), causal mask on diagonal tile
      #pragma unroll
      for (int j = 0; j < 8; ++j)
        #pragma unroll
        for (int r = 0; r < 4; ++r) {
          int row_g = qrow0 + i*16 + quad*4 + r;
          int col_g = kt*128 + j*16 + l16;
          float x = s[i][j][r]*0.125f + slope*(float)(row_g - col_g);
          if (diag && (col_g > row_g)) x = -1e9f;
          s[i][j][r] = x;
        }
      // online softmax per row (row lives in 16 lanes: shuffle-reduce over low 4 lane bits)
      #pragma unroll
      for (int r = 0; r < 4; ++r) {
        float mx = s[i][0][r];
        #pragma unroll
        for (int j = 1; j < 8; ++j) mx = fmaxf(mx, s[i][j][r]);
        #pragma unroll
        for (int d = 1; d < 16; d <<= 1) mx = fmaxf(mx, __shfl_xor(mx, d, 64));
        float mnew  = fmaxf(m_i[i][r], mx);
        float alpha = __expf(m_i[i][r] - mnew);
        m_i[i][r] = mnew;
        float rs = 0.f;
        #pragma unroll
        for (int j = 0; j < 8; ++j) {
          float p = __expf(s[i][j][r] - mnew);
          s[i][j][r] = p;
          rs += p;
        }
        #pragma unroll
        for (int d = 1; d < 16; d <<= 1) rs += __shfl_xor(rs, d, 64);
        l_i[i][r] = l_i[i][r]*alpha + rs;
        #pragma unroll
        for (int jn = 0; jn < 4; ++jn) o[i][jn][r] *= alpha;
      }
      // P (C/D layout) -> LDS bf16 (wave-private region; wave-local RAW is in-order)
      #pragma unroll
      for (int j = 0; j < 8; ++j)
        #pragma unroll
        for (int r = 0; r < 4; ++r)
          Ps[w][i*16 + quad*4 + r][j*16 + l16] = f2bf(s[i][j][r]);
    }

    // O += P V   (A from Ps, B from Vs)
    #pragma unroll
    for (int ks = 0; ks < 4; ++ks) {
      bf16x8 pa[2];
      #pragma unroll
      for (int i = 0; i < 2; ++i) pa[i] = *(const bf16x8*)&Ps[w][i*16 + l16][ks*32 + quad*8];
      #pragma unroll
      for (int jn = 0; jn < 4; ++jn) {
        bf16x8 vf = *(const bf16x8*)&Vs[jn*16 + l16][ks*32 + quad*8];
        #pragma unroll
        for (int i = 0; i < 2; ++i)
          o[i][jn] = __builtin_amdgcn_mfma_f32_16x16x32_bf16(pa[i], vf, o[i][jn], 0, 0, 0);
      }
    }
  }

  // epilogue: O / l_i -> concat buffer [B,S,P] bf16
  #pragma unroll
  for (int i = 0; i < 2; ++i)
    #pragma unroll
    for (int jn = 0; jn < 4; ++jn)
      #pragma unroll
      for (int r = 0; r < 4; ++r) {
        int row_g = qrow0 + i*16 + quad*4 + r;
        float vv = o[i][jn][r] / l_i[i][r];
        Ob[((long)(b*S_ + row_g))*P_ + h*KD_ + jn*16 + l16] = f2bf(vv);
      }
}

extern "C" void kernel_launch(void* const* d_in, const int* in_sizes, int n_in,
                              void* d_out, int out_size, void* d_ws, size_t ws_size,
                              hipStream_t stream) {
  const float* q  = (const float*)d_in[0];
  const float* k  = (const float*)d_in[1];
  const float* v  = (const float*)d_in[2];
  const float* Wq = (const float*)d_in[3];
  const float* bq = (const float*)d_in[4];
  const float* Wk = (const float*)d_in[5];
  const float* bk = (const float*)d_in[6];
  const float* Wv = (const float*)d_in[7];
  const float* bv = (const float*)d_in[8];
  const float* Wo = (const float*)d_in[9];
  const float* bo = (const float*)d_in[10];

  const size_t X_ELEMS = (size_t)M_ * P_;   // 8388608
  const size_t W_ELEMS = (size_t)D_ * P_;   // 1048576
  u16* ws  = (u16*)d_ws;
  u16* Xq  = ws;                 // bf16 copies of inputs
  u16* Xk  = Xq  + X_ELEMS;
  u16* Xv  = Xk  + X_ELEMS;
  u16* WqT = Xv  + X_ELEMS;      // transposed bf16 weights [N][K]
  u16* WkT = WqT + W_ELEMS;
  u16* WvT = WkT + W_ELEMS;
  u16* WoT = WvT + W_ELEMS;
  u16* Qb  = WoT + W_ELEMS;      // projections [B*S][P] bf16
  u16* Kb  = Qb  + X_ELEMS;
  u16* Vb  = Kb  + X_ELEMS;
  u16* Attn = Xq;                // reuse: Xq dead after Q projection

  // 1. convert inputs to bf16
  dim3 cvtGrid((unsigned)(X_ELEMS/4/256));
  cvt_bf16_kernel<<<cvtGrid, 256, 0, stream>>>(q, Xq, (int)(X_ELEMS/4));
  cvt_bf16_kernel<<<cvtGrid, 256, 0, stream>>>(k, Xk, (int)(X_ELEMS/4));
  cvt_bf16_kernel<<<cvtGrid, 256, 0, stream>>>(v, Xv, (int)(X_ELEMS/4));

  // 2. transpose weights to [N][K] bf16
  dim3 tg(32, 32), tb(32, 8);
  transpose_cvt<<<tg, tb, 0, stream>>>(Wq, WqT);
  transpose_cvt<<<tg, tb, 0, stream>>>(Wk, WkT);
  transpose_cvt<<<tg, tb, 0, stream>>>(Wv, WvT);
  transpose_cvt<<<tg, tb, 0, stream>>>(Wo, WoT);

  // 3. QKV projections (bf16 out)
  dim3 gg(M_/128, P_/128); // (64, 8)
  gemm_bt<true><<<gg, 256, 0, stream>>>(Xq, WqT, bq, Qb);
  gemm_bt<true><<<gg, 256, 0, stream>>>(Xk, WkT, bk, Kb);
  gemm_bt<true><<<gg, 256, 0, stream>>>(Xv, WvT, bv, Vb);

  // 4. fused causal+ALiBi flash attention
  attn_kernel<<<dim3(16, 16, 4), 256, 0, stream>>>(Qb, Kb, Vb, Attn);

  // 5. output projection (fp32 out + bias)
  gemm_bt<false><<<gg, 256, 0, stream>>>(Attn, WoT, bo, d_out);
}

// Round 2
// 492.265 us; speedup vs baseline: 1.6392x; 1.6392x over previous
//
#include <hip/hip_runtime.h>

#define B_ 4
#define S_ 2048
#define D_ 1024
#define H_ 16
#define KD_ 64
#define P_ 1024
#define M_ (B_*S_)

typedef unsigned short u16;
typedef unsigned int u32;
typedef __attribute__((ext_vector_type(4))) float f32x4;
typedef __attribute__((ext_vector_type(8))) __bf16 bf16x8;

__device__ __forceinline__ u16 f2bf(float f) {
  u32 x = __float_as_uint(f);
  return (u16)((x + 0x7fffu + ((x >> 16) & 1u)) >> 16);
}

__device__ __forceinline__ void gl_lds16(const u16* g, u16* l) {
  __builtin_amdgcn_global_load_lds((__attribute__((address_space(1))) void*)g,
                                   (__attribute__((address_space(3))) void*)l, 16, 0, 0);
}

// ---------------- fp32 -> bf16 convert (vectorized) ----------------
__global__ void cvt_bf16_kernel(const float* __restrict__ in, u16* __restrict__ out, int n4) {
  int i = blockIdx.x * 256 + threadIdx.x;
  if (i >= n4) return;
  float4 v = ((const float4*)in)[i];
  u32 w0 = (u32)f2bf(v.x) | ((u32)f2bf(v.y) << 16);
  u32 w1 = (u32)f2bf(v.z) | ((u32)f2bf(v.w) << 16);
  ((u32*)out)[i*2+0] = w0;
  ((u32*)out)[i*2+1] = w1;
}

// ---------------- transpose 1024x1024 fp32 -> bf16 [C][R] ----------------
__global__ void transpose_cvt(const float* __restrict__ in, u16* __restrict__ out) {
  __shared__ float tile[32][33];
  int bx = blockIdx.x * 32, by = blockIdx.y * 32;
  int tx = threadIdx.x, ty = threadIdx.y; // block (32,8)
  #pragma unroll
  for (int kk = 0; kk < 4; ++kk)
    tile[ty + kk*8][tx] = in[(by + ty + kk*8) * 1024 + bx + tx];
  __syncthreads();
  #pragma unroll
  for (int kk = 0; kk < 4; ++kk)
    out[(bx + ty + kk*8) * 1024 + by + tx] = f2bf(tile[tx][ty + kk*8]);
}

// ---------------- bf16 GEMM: C[M,N] = A[M,K] * Bt[N,K]^T + bias ----------------
template<bool BF16_OUT>
__global__ __launch_bounds__(256) void gemm_bt(const u16* __restrict__ A,
                                               const u16* __restrict__ Bt,
                                               const float* __restrict__ bias,
                                               void* __restrict__ Cout)
{
  constexpr int K = 1024, N = 1024, BK = 32;
  __shared__ alignas(16) u16 As[128*BK];
  __shared__ alignas(16) u16 Bs[128*BK];
  const int tid = threadIdx.x;
  const int w = tid >> 6, l = tid & 63;
  const int quad = l >> 4, l16 = l & 15;
  const int wm = (w >> 1) * 64, wn = (w & 1) * 64;
  const long mBase = (long)blockIdx.x * 128;
  const int  nBase = blockIdx.y * 128;

  f32x4 acc[4][4] = {};
  const int off0 = w*1024 + l*16;

  for (int kb = 0; kb < K/BK; ++kb) {
    __syncthreads();
    #pragma unroll
    for (int p = 0; p < 2; ++p) {
      int off = p*4096 + off0;
      int row = off >> 6;
      int cb  = off & 63;
      const u16* ga = A  + (mBase + row)*K + kb*BK + (cb >> 1);
      const u16* gb = Bt + ((long)(nBase + row))*K + kb*BK + (cb >> 1);
      gl_lds16(ga, (u16*)((char*)As + p*4096 + w*1024));
      gl_lds16(gb, (u16*)((char*)Bs + p*4096 + w*1024));
    }
    __syncthreads();
    bf16x8 af[4], bf[4];
    #pragma unroll
    for (int i = 0; i < 4; ++i) af[i] = *(const bf16x8*)&As[(wm + i*16 + l16)*BK + quad*8];
    #pragma unroll
    for (int j = 0; j < 4; ++j) bf[j] = *(const bf16x8*)&Bs[(wn + j*16 + l16)*BK + quad*8];
    #pragma unroll
    for (int i = 0; i < 4; ++i)
      #pragma unroll
      for (int j = 0; j < 4; ++j)
        acc[i][j] = __builtin_amdgcn_mfma_f32_16x16x32_bf16(af[i], bf[j], acc[i][j], 0, 0, 0);
  }

  #pragma unroll
  for (int i = 0; i < 4; ++i)
    #pragma unroll
    for (int j = 0; j < 4; ++j)
      #pragma unroll
      for (int r = 0; r < 4; ++r) {
        long row = mBase + wm + i*16 + quad*4 + r;
        int  col = nBase + wn + j*16 + l16;
        float v = acc[i][j][r] + bias[col];
        if (BF16_OUT) ((u16*)Cout)[row*N + col] = f2bf(v);
        else          ((float*)Cout)[row*N + col] = v;
      }
}

// ---------------- flash attention with ALiBi + causal ----------------
// grid (h=16, b=4, qtr=16), qt = 15 - qtr  -> long blocks dispatch FIRST.
// 256 threads (4 waves), wave w owns q-rows [w*32, w*32+32).
// LDS rows padded to 136 elems (16B-aligned, stride != 0 mod 32 banks).
// V double-buffered: next tile prefetched to VGPRs at iter start, written to
// LDS at iter end -> the single barrier never drains fresh global loads.
#define VPAD 136
__global__ __launch_bounds__(256, 3) void attn_kernel(const u16* __restrict__ Qb,
                                                      const u16* __restrict__ Kb,
                                                      const u16* __restrict__ Vb,
                                                      u16* __restrict__ Ob)
{
  const int h = blockIdx.x, b = blockIdx.y;
  const int qt = 15 - blockIdx.z;
  const int tid = threadIdx.x;
  const int w = tid >> 6, l = tid & 63;
  const int quad = l >> 4, l16 = l & 15;
  const float LOG2E = 1.44269504089f;
  const float slope = exp2f(-0.5f * (float)(h + 1));
  const float c1  = 0.125f * LOG2E;   // 1/sqrt(64) in log2 domain
  const float sl2 = slope * LOG2E;

  __shared__ alignas(16) u16 Vs[2][64][VPAD];   // [buf][d][key]
  __shared__ alignas(16) u16 Ps[4][16][VPAD];   // per-wave P tile (16 q-rows)

  const int qrow0 = qt*128 + w*32;

  // V staging: lane -> (key col, d chunk). 32 consecutive key cols per half-wave
  // -> LDS staging writes land 2-way (free); loads are 16B/lane (L1-friendly).
  const int vkr = tid & 31;     // + it*32
  const int vdc = tid >> 5;     // 0..7
  const u16* Vbase = Vb + ((long)b*S_)*P_ + h*KD_ + vdc*8;

  // Q fragments (A-operand layout), resident all kernel
  bf16x8 qf[2][2];
  #pragma unroll
  for (int i = 0; i < 2; ++i)
    #pragma unroll
    for (int kk = 0; kk < 2; ++kk)
      qf[i][kk] = *(const bf16x8*)&Qb[((long)(b*S_ + qrow0 + i*16 + l16))*P_ + h*KD_ + kk*32 + quad*8];

  f32x4 o[2][4] = {};
  float m_i[2][4], l_i[2][4];
  #pragma unroll
  for (int i = 0; i < 2; ++i)
    #pragma unroll
    for (int r = 0; r < 4; ++r) { m_i[i][r] = -1e30f; l_i[i][r] = 0.f; }

  // ---- prologue: stage V(0) ----
  uint4 vreg[4];
  #pragma unroll
  for (int it = 0; it < 4; ++it)
    vreg[it] = *(const uint4*)&Vbase[(long)(it*32 + vkr) * P_];
  #pragma unroll
  for (int it = 0; it < 4; ++it) {
    uint4 vv = vreg[it];
    u16* p = &Vs[0][vdc*8][it*32 + vkr];
    p[0*VPAD] = (u16)vv.x;  p[1*VPAD] = (u16)(vv.x >> 16);
    p[2*VPAD] = (u16)vv.y;  p[3*VPAD] = (u16)(vv.y >> 16);
    p[4*VPAD] = (u16)vv.z;  p[5*VPAD] = (u16)(vv.z >> 16);
    p[6*VPAD] = (u16)vv.w;  p[7*VPAD] = (u16)(vv.w >> 16);
  }
  __syncthreads();

  for (int kt = 0; kt <= qt; ++kt) {
    const int cur = kt & 1;
    const bool last = (kt == qt);
    // prefetch next V tile into registers (overlaps entire compute phase)
    if (!last) {
      const int ktn = kt + 1;
      #pragma unroll
      for (int it = 0; it < 4; ++it)
        vreg[it] = *(const uint4*)&Vbase[(long)(ktn*128 + it*32 + vkr) * P_];
    }

    // ALiBi column terms (log2 domain), shared by both q-sub-tiles
    float colt[8];
    #pragma unroll
    for (int j = 0; j < 8; ++j)
      colt[j] = sl2 * (float)(kt*128 + j*16 + l16);
    const bool diag = (kt == qt);

    #pragma unroll
    for (int i = 0; i < 2; ++i) {
      // ---- S = Q K^T (K fragments direct from global; L1-hot across waves)
      f32x4 s[8];
      #pragma unroll
      for (int j = 0; j < 8; ++j) {
        const u16* kp = Kb + ((long)(b*S_ + kt*128 + j*16 + l16))*P_ + h*KD_;
        bf16x8 kf0 = *(const bf16x8*)(kp + quad*8);
        bf16x8 kf1 = *(const bf16x8*)(kp + 32 + quad*8);
        f32x4 t = {};
        t = __builtin_amdgcn_mfma_f32_16x16x32_bf16(qf[i][0], kf0, t, 0, 0, 0);
        t = __builtin_amdgcn_mfma_f32_16x16x32_bf16(qf[i][1], kf1, t, 0, 0, 0);
        s[j] = t;
      }

      // ---- logits in log2 domain + causal mask
      #pragma unroll
      for (int r = 0; r < 4; ++r) {
        const int   row_g = qrow0 + i*16 + quad*4 + r;
        const float rowt  = sl2 * (float)row_g;
        #pragma unroll
        for (int j = 0; j < 8; ++j)
          s[j][r] = fmaf(s[j][r], c1, rowt) - colt[j];
        if (diag) {
          #pragma unroll
          for (int j = 0; j < 8; ++j) {
            int col_g = kt*128 + j*16 + l16;
            if (col_g > row_g) s[j][r] = -1e30f;
          }
        }
        // ---- online softmax (row lives in 16 lanes)
        float mx = s[0][r];
        #pragma unroll
        for (int j = 1; j < 8; ++j) mx = fmaxf(mx, s[j][r]);
        #pragma unroll
        for (int d = 1; d < 16; d <<= 1) mx = fmaxf(mx, __shfl_xor(mx, d, 64));
        float mnew  = fmaxf(m_i[i][r], mx);
        float alpha = __builtin_amdgcn_exp2f(m_i[i][r] - mnew);
        m_i[i][r] = mnew;
        float rs = 0.f;
        #pragma unroll
        for (int j = 0; j < 8; ++j) {
          float p = __builtin_amdgcn_exp2f(s[j][r] - mnew);
          s[j][r] = p;
          rs += p;
        }
        #pragma unroll
        for (int d = 1; d < 16; d <<= 1) rs += __shfl_xor(rs, d, 64);
        l_i[i][r] = l_i[i][r]*alpha + rs;
        #pragma unroll
        for (int jn = 0; jn < 4; ++jn) o[i][jn][r] *= alpha;
        // P (C/D layout) -> wave-private LDS (in-order pipe, no barrier)
        #pragma unroll
        for (int j = 0; j < 8; ++j)
          Ps[w][quad*4 + r][j*16 + l16] = f2bf(s[j][r]);
      }

      // ---- O += P V
      #pragma unroll
      for (int ks = 0; ks < 4; ++ks) {
        bf16x8 pa = *(const bf16x8*)&Ps[w][l16][ks*32 + quad*8];
        #pragma unroll
        for (int jn = 0; jn < 4; ++jn) {
          bf16x8 vf = *(const bf16x8*)&Vs[cur][jn*16 + l16][ks*32 + quad*8];
          o[i][jn] = __builtin_amdgcn_mfma_f32_16x16x32_bf16(pa, vf, o[i][jn], 0, 0, 0);
        }
      }
    }

    // ---- commit prefetched V to the other buffer; single barrier per iter
    if (!last) {
      const int nxt = cur ^ 1;
      #pragma unroll
      for (int it = 0; it < 4; ++it) {
        uint4 vv = vreg[it];
        u16* p = &Vs[nxt][vdc*8][it*32 + vkr];
        p[0*VPAD] = (u16)vv.x;  p[1*VPAD] = (u16)(vv.x >> 16);
        p[2*VPAD] = (u16)vv.y;  p[3*VPAD] = (u16)(vv.y >> 16);
        p[4*VPAD] = (u16)vv.z;  p[5*VPAD] = (u16)(vv.z >> 16);
        p[6*VPAD] = (u16)vv.w;  p[7*VPAD] = (u16)(vv.w >> 16);
      }
      __syncthreads();
    }
  }

  // ---- epilogue
  #pragma unroll
  for (int i = 0; i < 2; ++i)
    #pragma unroll
    for (int jn = 0; jn < 4; ++jn)
      #pragma unroll
      for (int r = 0; r < 4; ++r) {
        int row_g = qrow0 + i*16 + quad*4 + r;
        float vv = o[i][jn][r] / l_i[i][r];
        Ob[((long)(b*S_ + row_g))*P_ + h*KD_ + jn*16 + l16] = f2bf(vv);
      }
}

extern "C" void kernel_launch(void* const* d_in, const int* in_sizes, int n_in,
                              void* d_out, int out_size, void* d_ws, size_t ws_size,
                              hipStream_t stream) {
  const float* q  = (const float*)d_in[0];
  const float* k  = (const float*)d_in[1];
  const float* v  = (const float*)d_in[2];
  const float* Wq = (const float*)d_in[3];
  const float* bq = (const float*)d_in[4];
  const float* Wk = (const float*)d_in[5];
  const float* bk = (const float*)d_in[6];
  const float* Wv = (const float*)d_in[7];
  const float* bv = (const float*)d_in[8];
  const float* Wo = (const float*)d_in[9];
  const float* bo = (const float*)d_in[10];

  const size_t X_ELEMS = (size_t)M_ * P_;
  const size_t W_ELEMS = (size_t)D_ * P_;
  u16* ws  = (u16*)d_ws;
  u16* Xq  = ws;
  u16* Xk  = Xq  + X_ELEMS;
  u16* Xv  = Xk  + X_ELEMS;
  u16* WqT = Xv  + X_ELEMS;
  u16* WkT = WqT + W_ELEMS;
  u16* WvT = WkT + W_ELEMS;
  u16* WoT = WvT + W_ELEMS;
  u16* Qb  = WoT + W_ELEMS;
  u16* Kb  = Qb  + X_ELEMS;
  u16* Vb  = Kb  + X_ELEMS;
  u16* Attn = Xq;  // reuse: Xq dead after Q projection

  dim3 cvtGrid((unsigned)(X_ELEMS/4/256));
  cvt_bf16_kernel<<<cvtGrid, 256, 0, stream>>>(q, Xq, (int)(X_ELEMS/4));
  cvt_bf16_kernel<<<cvtGrid, 256, 0, stream>>>(k, Xk, (int)(X_ELEMS/4));
  cvt_bf16_kernel<<<cvtGrid, 256, 0, stream>>>(v, Xv, (int)(X_ELEMS/4));

  dim3 tg(32, 32), tb(32, 8);
  transpose_cvt<<<tg, tb, 0, stream>>>(Wq, WqT);
  transpose_cvt<<<tg, tb, 0, stream>>>(Wk, WkT);
  transpose_cvt<<<tg, tb, 0, stream>>>(Wv, WvT);
  transpose_cvt<<<tg, tb, 0, stream>>>(Wo, WoT);

  dim3 gg(M_/128, P_/128);
  gemm_bt<true><<<gg, 256, 0, stream>>>(Xq, WqT, bq, Qb);
  gemm_bt<true><<<gg, 256, 0, stream>>>(Xk, WkT, bk, Kb);
  gemm_bt<true><<<gg, 256, 0, stream>>>(Xv, WvT, bv, Vb);

  attn_kernel<<<dim3(16, 4, 16), 256, 0, stream>>>(Qb, Kb, Vb, Attn);

  gemm_bt<false><<<gg, 256, 0, stream>>>(Attn, WoT, bo, d_out);
}

// Round 4
// 404.791 us; speedup vs baseline: 1.9934x; 1.2161x over previous
//
#include <hip/hip_runtime.h>

#define B_ 4
#define S_ 2048
#define D_ 1024
#define H_ 16
#define KD_ 64
#define P_ 1024
#define M_ (B_*S_)

typedef unsigned short u16;
typedef unsigned int u32;
typedef __attribute__((ext_vector_type(4))) float f32x4;
typedef __attribute__((ext_vector_type(8))) __bf16 bf16x8;

__device__ __forceinline__ u16 f2bf(float f) {
  u32 x = __float_as_uint(f);
  return (u16)((x + 0x7fffu + ((x >> 16) & 1u)) >> 16);
}

__device__ __forceinline__ void gl_lds16(const u16* g, u16* l) {
  __builtin_amdgcn_global_load_lds((__attribute__((address_space(1))) void*)g,
                                   (__attribute__((address_space(3))) void*)l, 16, 0, 0);
}

// pack bf16(b)<<16 | bf16(a), round-to-nearest (+0x8000 then take hi16 via v_perm)
__device__ __forceinline__ u32 pkbf(float a, float b) {
  return __builtin_amdgcn_perm(__float_as_uint(b) + 0x8000u,
                               __float_as_uint(a) + 0x8000u, 0x07060302u);
}

// ---------------- fp32 -> bf16 convert, 3 tensors in one launch ----------------
__global__ void cvt3_kernel(const float* __restrict__ q, const float* __restrict__ k,
                            const float* __restrict__ v,
                            u16* __restrict__ Xq, u16* __restrict__ Xk, u16* __restrict__ Xv) {
  const int z = blockIdx.y;
  const float* in = z == 0 ? q : z == 1 ? k : v;
  u16* out = z == 0 ? Xq : z == 1 ? Xk : Xv;
  int i = blockIdx.x * 256 + threadIdx.x;
  float4 vv = ((const float4*)in)[i];
  ((u32*)out)[i*2+0] = (u32)f2bf(vv.x) | ((u32)f2bf(vv.y) << 16);
  ((u32*)out)[i*2+1] = (u32)f2bf(vv.z) | ((u32)f2bf(vv.w) << 16);
}

// ---------------- transpose 1024x1024 fp32 -> bf16 [C][R], 4 weights ----------------
__global__ void transpose_cvt4(const float* __restrict__ Wq, const float* __restrict__ Wk,
                               const float* __restrict__ Wv, const float* __restrict__ Wo,
                               u16* __restrict__ WqT, u16* __restrict__ WkT,
                               u16* __restrict__ WvT, u16* __restrict__ WoT) {
  const int z = blockIdx.z;
  const float* in = z == 0 ? Wq : z == 1 ? Wk : z == 2 ? Wv : Wo;
  u16* out = z == 0 ? WqT : z == 1 ? WkT : z == 2 ? WvT : WoT;
  __shared__ float tile[32][33];
  int bx = blockIdx.x * 32, by = blockIdx.y * 32;
  int tx = threadIdx.x, ty = threadIdx.y; // block (32,8)
  #pragma unroll
  for (int kk = 0; kk < 4; ++kk)
    tile[ty + kk*8][tx] = in[(by + ty + kk*8) * 1024 + bx + tx];
  __syncthreads();
  #pragma unroll
  for (int kk = 0; kk < 4; ++kk)
    out[(bx + ty + kk*8) * 1024 + by + tx] = f2bf(tile[tx][ty + kk*8]);
}

// ---------------- QKV projection GEMM (batched, z selects), m97 pattern ----------------
// z=0: Q -> Qb [row][P]; z=1: K -> Kb [row][P]; z=2: V -> Vt [b][h][d][s] (transposed!)
__global__ __launch_bounds__(256) void gemm_qkv(
    const u16* __restrict__ Xq, const u16* __restrict__ Xk, const u16* __restrict__ Xv,
    const u16* __restrict__ WqT, const u16* __restrict__ WkT, const u16* __restrict__ WvT,
    const float* __restrict__ bq, const float* __restrict__ bk, const float* __restrict__ bv,
    u16* __restrict__ Qb, u16* __restrict__ Kb, u16* __restrict__ Vt)
{
  constexpr int K = 1024, N = 1024, BK = 32;
  const int z = blockIdx.z;
  const u16* A  = z == 0 ? Xq  : z == 1 ? Xk  : Xv;
  const u16* Bt = z == 0 ? WqT : z == 1 ? WkT : WvT;
  const float* bias = z == 0 ? bq : z == 1 ? bk : bv;

  __shared__ alignas(16) u16 As[128*BK];
  __shared__ alignas(16) u16 Bs[128*BK];
  const int tid = threadIdx.x;
  const int w = tid >> 6, l = tid & 63;
  const int quad = l >> 4, l16 = l & 15;
  const int wm = (w >> 1) * 64, wn = (w & 1) * 64;
  const long mBase = (long)blockIdx.x * 128;
  const int  nBase = blockIdx.y * 128;

  f32x4 acc[4][4] = {};
  const int off0 = w*1024 + l*16;

  for (int kb = 0; kb < K/BK; ++kb) {
    __syncthreads();
    #pragma unroll
    for (int p = 0; p < 2; ++p) {
      int off = p*4096 + off0;
      int row = off >> 6;
      int cb  = off & 63;
      const u16* ga = A  + (mBase + row)*K + kb*BK + (cb >> 1);
      const u16* gb = Bt + ((long)(nBase + row))*K + kb*BK + (cb >> 1);
      gl_lds16(ga, (u16*)((char*)As + p*4096 + w*1024));
      gl_lds16(gb, (u16*)((char*)Bs + p*4096 + w*1024));
    }
    __syncthreads();
    bf16x8 af[4], bf[4];
    #pragma unroll
    for (int i = 0; i < 4; ++i) af[i] = *(const bf16x8*)&As[(wm + i*16 + l16)*BK + quad*8];
    #pragma unroll
    for (int j = 0; j < 4; ++j) bf[j] = *(const bf16x8*)&Bs[(wn + j*16 + l16)*BK + quad*8];
    #pragma unroll
    for (int i = 0; i < 4; ++i)
      #pragma unroll
      for (int j = 0; j < 4; ++j)
        acc[i][j] = __builtin_amdgcn_mfma_f32_16x16x32_bf16(af[i], bf[j], acc[i][j], 0, 0, 0);
  }

  if (z < 2) {
    u16* Cout = z == 0 ? Qb : Kb;
    #pragma unroll
    for (int i = 0; i < 4; ++i)
      #pragma unroll
      for (int j = 0; j < 4; ++j)
        #pragma unroll
        for (int r = 0; r < 4; ++r) {
          long row = mBase + wm + i*16 + quad*4 + r;
          int  col = nBase + wn + j*16 + l16;
          Cout[row*N + col] = f2bf(acc[i][j][r] + bias[col]);
        }
  } else {
    // V: write transposed per head: Vt[(b*1024 + h*64 + d)*2048 + s]; 4 consecutive s -> 8B stores
    #pragma unroll
    for (int i = 0; i < 4; ++i)
      #pragma unroll
      for (int j = 0; j < 4; ++j) {
        int  col  = nBase + wn + j*16 + l16;       // = h*64+d
        long row0 = mBase + wm + i*16 + quad*4;    // token; +r consecutive
        int  bb = (int)(row0 >> 11);
        int  ss = (int)(row0 & 2047);
        float bcol = bias[col];
        float v0 = acc[i][j][0] + bcol, v1 = acc[i][j][1] + bcol;
        float v2 = acc[i][j][2] + bcol, v3 = acc[i][j][3] + bcol;
        uint2 pk;
        pk.x = (u32)f2bf(v0) | ((u32)f2bf(v1) << 16);
        pk.y = (u32)f2bf(v2) | ((u32)f2bf(v3) << 16);
        *(uint2*)&Vt[((long)(bb*16) * 64 + col) * 2048 + ss] = pk;
      }
  }
}

// ---------------- output projection GEMM (fp32 out) ----------------
__global__ __launch_bounds__(256) void gemm_out(const u16* __restrict__ A,
                                                const u16* __restrict__ Bt,
                                                const float* __restrict__ bias,
                                                float* __restrict__ Cout)
{
  constexpr int K = 1024, N = 1024, BK = 32;
  __shared__ alignas(16) u16 As[128*BK];
  __shared__ alignas(16) u16 Bs[128*BK];
  const int tid = threadIdx.x;
  const int w = tid >> 6, l = tid & 63;
  const int quad = l >> 4, l16 = l & 15;
  const int wm = (w >> 1) * 64, wn = (w & 1) * 64;
  const long mBase = (long)blockIdx.x * 128;
  const int  nBase = blockIdx.y * 128;

  f32x4 acc[4][4] = {};
  const int off0 = w*1024 + l*16;

  for (int kb = 0; kb < K/BK; ++kb) {
    __syncthreads();
    #pragma unroll
    for (int p = 0; p < 2; ++p) {
      int off = p*4096 + off0;
      int row = off >> 6;
      int cb  = off & 63;
      const u16* ga = A  + (mBase + row)*K + kb*BK + (cb >> 1);
      const u16* gb = Bt + ((long)(nBase + row))*K + kb*BK + (cb >> 1);
      gl_lds16(ga, (u16*)((char*)As + p*4096 + w*1024));
      gl_lds16(gb, (u16*)((char*)Bs + p*4096 + w*1024));
    }
    __syncthreads();
    bf16x8 af[4], bf[4];
    #pragma unroll
    for (int i = 0; i < 4; ++i) af[i] = *(const bf16x8*)&As[(wm + i*16 + l16)*BK + quad*8];
    #pragma unroll
    for (int j = 0; j < 4; ++j) bf[j] = *(const bf16x8*)&Bs[(wn + j*16 + l16)*BK + quad*8];
    #pragma unroll
    for (int i = 0; i < 4; ++i)
      #pragma unroll
      for (int j = 0; j < 4; ++j)
        acc[i][j] = __builtin_amdgcn_mfma_f32_16x16x32_bf16(af[i], bf[j], acc[i][j], 0, 0, 0);
  }

  #pragma unroll
  for (int i = 0; i < 4; ++i)
    #pragma unroll
    for (int j = 0; j < 4; ++j)
      #pragma unroll
      for (int r = 0; r < 4; ++r) {
        long row = mBase + wm + i*16 + quad*4 + r;
        int  col = nBase + wn + j*16 + l16;
        Cout[row*N + col] = acc[i][j][r] + bias[col];
      }
}

// ---------------- flash attention: barrier-free, one wave per block ----------------
// grid 4096 = qtr(16, qt=15 first) x [b(4) x h(16) x w(4)]; 64 threads.
// S^T = K*Q^T (swapped operands) so P packs as b64 LDS writes; PV = V^T * P^T with
// V^T fragments loaded straight from global (pre-transposed Vt) -> NO barriers at all.
// Static-shift softmax: reference ALiBi is +slope*(q-k) (grows with distance!), so
// shift by its k=0 value sl2*q per row -> exponent = c1*s - sl2*k, bounded ~[-inf, +10].
// Distant-key underflow to 0 is exact (true weights ~2^-2000). No max, no rescale.
#define PST 136
__global__ __launch_bounds__(64, 3) void attn_kernel(const u16* __restrict__ Qb,
                                                     const u16* __restrict__ Kb,
                                                     const u16* __restrict__ Vt,
                                                     u16* __restrict__ Ob)
{
  const int n = blockIdx.x;
  const int qt = 15 - (n >> 8);
  const int r8 = n & 255;
  const int b = r8 >> 6, h = (r8 >> 2) & 15, w = r8 & 3;
  const int l = threadIdx.x;
  const int quad = l >> 4, l16 = l & 15;
  const float LOG2E = 1.44269504089f;
  const float slope = exp2f(-0.5f * (float)(h + 1));
  const float c1  = 0.125f * LOG2E;
  const float sl2 = slope * LOG2E;

  __shared__ alignas(16) u16 Ps[2][16][PST];   // P rows = q (16 per sub-tile), cols = key

  const int q0 = qt*128 + w*32;
  const u16* Qp = Qb + ((long)(b*S_ + q0))*P_ + h*KD_;
  const u16* Kp = Kb + ((long)(b*S_))*P_ + h*KD_;
  const u16* Vp = Vt + ((long)(b*H_ + h))*KD_*S_;

  // Q fragments (serve as MFMA B-operand for S^T = K*Q^T)
  bf16x8 qf[2][2];
  #pragma unroll
  for (int i = 0; i < 2; ++i)
    #pragma unroll
    for (int kk = 0; kk < 2; ++kk)
      qf[i][kk] = *(const bf16x8*)&Qp[(long)(i*16 + l16)*P_ + kk*32 + quad*8];

  f32x4 o[2][4] = {};           // O^T accumulators: rows d, cols q=l16
  float lsum[2] = {0.f, 0.f};
  const float rs1 = sl2, rs2 = 2.f*sl2, rs3 = 3.f*sl2;

  // -------- full (non-diagonal) key tiles --------
  for (int kt = 0; kt < qt; ++kt) {
    const u16* kts = Kp + (long)(kt*128 + l16)*P_;
    #pragma unroll
    for (int jh = 0; jh < 2; ++jh) {
      f32x4 st[2][4];
      #pragma unroll
      for (int jj = 0; jj < 4; ++jj) {
        const int j = jh*4 + jj;
        const u16* kp = kts + (long)(j*16)*P_;
        bf16x8 kf0 = *(const bf16x8*)(kp + quad*8);
        bf16x8 kf1 = *(const bf16x8*)(kp + 32 + quad*8);
        #pragma unroll
        for (int i = 0; i < 2; ++i) {
          f32x4 t = {};
          t = __builtin_amdgcn_mfma_f32_16x16x32_bf16(kf0, qf[i][0], t, 0, 0, 0);
          t = __builtin_amdgcn_mfma_f32_16x16x32_bf16(kf1, qf[i][1], t, 0, 0, 0);
          st[i][jj] = t;
        }
      }
      #pragma unroll
      for (int i = 0; i < 2; ++i)
        #pragma unroll
        for (int jj = 0; jj < 4; ++jj) {
          const int j = jh*4 + jj;
          const float kb  = (float)(kt*128 + j*16 + quad*4);
          const float bij = -sl2 * kb;          // static shift: exponent = c1*s - sl2*k
          float p0 = __builtin_amdgcn_exp2f(fmaf(st[i][jj][0], c1, bij));
          float p1 = __builtin_amdgcn_exp2f(fmaf(st[i][jj][1], c1, bij) - rs1);
          float p2 = __builtin_amdgcn_exp2f(fmaf(st[i][jj][2], c1, bij) - rs2);
          float p3 = __builtin_amdgcn_exp2f(fmaf(st[i][jj][3], c1, bij) - rs3);
          lsum[i] += (p0 + p1) + (p2 + p3);
          uint2 pk; pk.x = pkbf(p0, p1); pk.y = pkbf(p2, p3);
          *(uint2*)&Ps[i][l16][j*16 + quad*4] = pk;
        }
    }
    // O^T += V^T * P^T
    #pragma unroll
    for (int ks = 0; ks < 4; ++ks) {
      bf16x8 pb0 = *(const bf16x8*)&Ps[0][l16][ks*32 + quad*8];
      bf16x8 pb1 = *(const bf16x8*)&Ps[1][l16][ks*32 + quad*8];
      #pragma unroll
      for (int jn = 0; jn < 4; ++jn) {
        bf16x8 vf = *(const bf16x8*)&Vp[(long)(jn*16 + l16)*S_ + kt*128 + ks*32 + quad*8];
        o[0][jn] = __builtin_amdgcn_mfma_f32_16x16x32_bf16(vf, pb0, o[0][jn], 0, 0, 0);
        o[1][jn] = __builtin_amdgcn_mfma_f32_16x16x32_bf16(vf, pb1, o[1][jn], 0, 0, 0);
      }
    }
  }

  // -------- diagonal tile (kt == qt): masked, partial j/ks ranges --------
  {
    const int kt = qt;
    const int jmax = 2*w + 2, ksmax = w + 1;
    const u16* kts = Kp + (long)(kt*128 + l16)*P_;
    for (int j = 0; j < jmax; ++j) {
      const u16* kp = kts + (long)(j*16)*P_;
      bf16x8 kf0 = *(const bf16x8*)(kp + quad*8);
      bf16x8 kf1 = *(const bf16x8*)(kp + 32 + quad*8);
      const int kl0 = j*16 + quad*4;            // tile-local key of r=0
      const float kb  = (float)(kt*128 + kl0);
      #pragma unroll
      for (int i = 0; i < 2; ++i) {
        f32x4 t = {};
        t = __builtin_amdgcn_mfma_f32_16x16x32_bf16(kf0, qf[i][0], t, 0, 0, 0);
        t = __builtin_amdgcn_mfma_f32_16x16x32_bf16(kf1, qf[i][1], t, 0, 0, 0);
        const int ql = w*32 + i*16 + l16;       // tile-local q row
        const float bij = -sl2 * kb;
        float x0 = fmaf(t[0], c1, bij);
        float x1 = fmaf(t[1], c1, bij) - rs1;
        float x2 = fmaf(t[2], c1, bij) - rs2;
        float x3 = fmaf(t[3], c1, bij) - rs3;
        if (kl0 + 0 > ql) x0 = -1e30f;
        if (kl0 + 1 > ql) x1 = -1e30f;
        if (kl0 + 2 > ql) x2 = -1e30f;
        if (kl0 + 3 > ql) x3 = -1e30f;
        float p0 = __builtin_amdgcn_exp2f(x0);
        float p1 = __builtin_amdgcn_exp2f(x1);
        float p2 = __builtin_amdgcn_exp2f(x2);
        float p3 = __builtin_amdgcn_exp2f(x3);
        lsum[i] += (p0 + p1) + (p2 + p3);
        uint2 pk; pk.x = pkbf(p0, p1); pk.y = pkbf(p2, p3);
        *(uint2*)&Ps[i][l16][j*16 + quad*4] = pk;
      }
    }
    for (int ks = 0; ks < ksmax; ++ks) {
      bf16x8 pb0 = *(const bf16x8*)&Ps[0][l16][ks*32 + quad*8];
      bf16x8 pb1 = *(const bf16x8*)&Ps[1][l16][ks*32 + quad*8];
      #pragma unroll
      for (int jn = 0; jn < 4; ++jn) {
        bf16x8 vf = *(const bf16x8*)&Vp[(long)(jn*16 + l16)*S_ + kt*128 + ks*32 + quad*8];
        o[0][jn] = __builtin_amdgcn_mfma_f32_16x16x32_bf16(vf, pb0, o[0][jn], 0, 0, 0);
        o[1][jn] = __builtin_amdgcn_mfma_f32_16x16x32_bf16(vf, pb1, o[1][jn], 0, 0, 0);
      }
    }
  }

  // -------- epilogue: reduce l across quads, scale, store (8B per lane-chunk) --------
  #pragma unroll
  for (int i = 0; i < 2; ++i) {
    lsum[i] += __shfl_xor(lsum[i], 16, 64);
    lsum[i] += __shfl_xor(lsum[i], 32, 64);
    const float inv = 1.0f / lsum[i];
    #pragma unroll
    for (int jn = 0; jn < 4; ++jn) {
      float v0 = o[i][jn][0] * inv, v1 = o[i][jn][1] * inv;
      float v2 = o[i][jn][2] * inv, v3 = o[i][jn][3] * inv;
      uint2 pk;
      pk.x = (u32)f2bf(v0) | ((u32)f2bf(v1) << 16);
      pk.y = (u32)f2bf(v2) | ((u32)f2bf(v3) << 16);
      *(uint2*)&Ob[((long)(b*S_ + q0 + i*16 + l16))*P_ + h*KD_ + jn*16 + quad*4] = pk;
    }
  }
}

extern "C" void kernel_launch(void* const* d_in, const int* in_sizes, int n_in,
                              void* d_out, int out_size, void* d_ws, size_t ws_size,
                              hipStream_t stream) {
  const float* q  = (const float*)d_in[0];
  const float* k  = (const float*)d_in[1];
  const float* v  = (const float*)d_in[2];
  const float* Wq = (const float*)d_in[3];
  const float* bq = (const float*)d_in[4];
  const float* Wk = (const float*)d_in[5];
  const float* bk = (const float*)d_in[6];
  const float* Wv = (const float*)d_in[7];
  const float* bv = (const float*)d_in[8];
  const float* Wo = (const float*)d_in[9];
  const float* bo = (const float*)d_in[10];

  const size_t X_ELEMS = (size_t)M_ * P_;
  const size_t W_ELEMS = (size_t)D_ * P_;
  u16* ws  = (u16*)d_ws;
  u16* Xq  = ws;
  u16* Xk  = Xq  + X_ELEMS;
  u16* Xv  = Xk  + X_ELEMS;
  u16* WqT = Xv  + X_ELEMS;
  u16* WkT = WqT + W_ELEMS;
  u16* WvT = WkT + W_ELEMS;
  u16* WoT = WvT + W_ELEMS;
  u16* Qb  = WoT + W_ELEMS;
  u16* Kb  = Qb  + X_ELEMS;
  u16* Vt  = Kb  + X_ELEMS;      // transposed V: [b][h][d][s]
  u16* Attn = Xq;                // reuse: Xq dead after projections

  cvt3_kernel<<<dim3((unsigned)(X_ELEMS/4/256), 3), 256, 0, stream>>>(q, k, v, Xq, Xk, Xv);

  transpose_cvt4<<<dim3(32, 32, 4), dim3(32, 8), 0, stream>>>(Wq, Wk, Wv, Wo,
                                                              WqT, WkT, WvT, WoT);

  gemm_qkv<<<dim3(M_/128, P_/128, 3), 256, 0, stream>>>(Xq, Xk, Xv, WqT, WkT, WvT,
                                                        bq, bk, bv, Qb, Kb, Vt);

  attn_kernel<<<dim3(4096), 64, 0, stream>>>(Qb, Kb, Vt, Attn);

  gemm_out<<<dim3(M_/128, P_/128), 256, 0, stream>>>(Attn, WoT, bo, (float*)d_out);
}